// Round 4
// baseline (2169.979 us; speedup 1.0000x reference)
//
#include <hip/hip_runtime.h>

// ---------------------------------------------------------------------------
// SpatialAttention3D: B=2, C=384, D=H=W=32, HEADS=12, HD=32, WS=5, PAD=2
// I/O dtype: float32 (per reference). Intermediates q/k/v/a: bf16 in ws.
// Per-batch pipeline (ws = 2 x 12,582,912 bf16 = 48 MiB, proven available):
//   for b in {0,1}:
//     1: qkv = x[b] @ w_qkv^T + b_qkv -> q (ws), k (d_out[b] half), v (ws)
//        layout [H][S][32] bf16, channel-last per voxel (64B chunks)
//     2: 5x5x5 neighborhood attention -> a (aliases q; race-free: each
//        thread reads only its own q, then writes a at that same address)
//     3: out[b] = a @ w_proj^T + b_proj -> d_out[b] f32 (overwrites k)
// ---------------------------------------------------------------------------

#define NB 2
#define NC 384
#define NHEADS 12
#define NHD 32
#define NS 32768               // 32*32*32
#define PERB 12582912          // NHEADS*NS*NHD == NC*NS (one batch)
#define SCALE_F 0.17677669529663687f
#define LOG2E_F 1.4426950408889634f

typedef unsigned short bfr;    // raw bf16 bits
typedef float floatx4 __attribute__((ext_vector_type(4)));

union F8 { floatx4 v[2]; float f[8]; };
union B8 { floatx4 v;    bfr  h[8]; };   // 8 bf16 in one 16B chunk

__device__ __forceinline__ float b2f(bfr u) {
    union { unsigned int i; float f; } v;
    v.i = (unsigned int)u << 16;
    return v.f;
}
__device__ __forceinline__ bfr f2b(float f) {
    union { float f; unsigned int i; } v;
    v.f = f;
    unsigned int x = v.i;
    return (bfr)((x + 0x7fffu + ((x >> 16) & 1u)) >> 16);  // RNE
}

// diagnostic: encode ws_size (MiB) into the output if ws is too small
__global__ void fill_code(float* out, float code) {
    for (size_t i = (size_t)blockIdx.x*256 + threadIdx.x; i < (size_t)NB*PERB;
         i += (size_t)gridDim.x*256) out[i] = code;
}

// ---------------------------------------------------------------------------
// Kernel 1: QKV GEMM for one batch (f32 in, bf16 out).
// x[b][c][s] * w[o][c] + bias[o] -> {q,k,v}[h][s][hd]
// tile: 64 outch x 256 pos, K-chunk 32. 256 threads, 8x8 reg tile each.
// ---------------------------------------------------------------------------
__global__ __launch_bounds__(256) void qkv_gemm(
    const float* __restrict__ x, const float* __restrict__ w,
    const float* __restrict__ bias,
    bfr* __restrict__ qT, bfr* __restrict__ kT, bfr* __restrict__ vT, int b)
{
    __shared__ __attribute__((aligned(16))) float xs[32][256];   // 32 KB
    __shared__ __attribute__((aligned(16))) float wsh[32][64];   //  8 KB
    const int tid  = threadIdx.x;
    const int pos0 = blockIdx.x * 256;
    const int o0   = blockIdx.y * 64;
    const int tx = tid & 31;      // pos group: pos = pos0 + tx*8 .. +8
    const int ty = tid >> 5;      // outch group: o = o0 + ty*8 .. +8

    float acc[8][8];
    #pragma unroll
    for (int j = 0; j < 8; ++j) {
        const float bv = bias[o0 + ty*8 + j];
        #pragma unroll
        for (int i = 0; i < 8; ++i) acc[i][j] = bv;
    }

    for (int kc = 0; kc < 12; ++kc) {
        const int c0 = kc * 32;
        // stage x chunk [32 ch][256 pos]: 2048 float4 units, coalesced
        #pragma unroll
        for (int g = 0; g < 8; ++g) {
            const int u  = g*256 + tid;
            const int kk = u >> 6;            // 0..31
            const int c4 = (u & 63) * 4;      // 0..252
            *(floatx4*)&xs[kk][c4] =
                *(const floatx4*)&x[((size_t)b*NC + c0 + kk)*NS + pos0 + c4];
        }
        // stage w transposed: wsh[kk][j] = w[o0+j][c0+kk]
        {
            const int j = tid >> 2, kg = tid & 3;
            F8 t;
            t.v[0] = *(const floatx4*)&w[(size_t)(o0 + j)*NC + c0 + kg*8];
            t.v[1] = *(const floatx4*)&w[(size_t)(o0 + j)*NC + c0 + kg*8 + 4];
            #pragma unroll
            for (int q = 0; q < 8; ++q) wsh[kg*8 + q][j] = t.f[q];
        }
        __syncthreads();
        #pragma unroll
        for (int kk = 0; kk < 32; ++kk) {
            F8 xv, wv;
            xv.v[0] = *(const floatx4*)&xs[kk][tx*8];
            xv.v[1] = *(const floatx4*)&xs[kk][tx*8 + 4];
            wv.v[0] = *(const floatx4*)&wsh[kk][ty*8];
            wv.v[1] = *(const floatx4*)&wsh[kk][ty*8 + 4];
            #pragma unroll
            for (int i = 0; i < 8; ++i)
                #pragma unroll
                for (int j = 0; j < 8; ++j)
                    acc[i][j] += xv.f[i] * wv.f[j];
        }
        __syncthreads();
    }

    // epilogue: bf16, transposed [h][s][hd]; 8-outch run stays in one head
    const int ob   = o0 + ty*8;
    const int tens = ob / NC;                 // 0=q, 1=k, 2=v
    const int rem  = ob - tens*NC;
    const int hh   = rem >> 5;
    const int cc0  = rem & 31;                // in {0,8,16,24}
    bfr* dstT = (tens == 0) ? qT : ((tens == 1) ? kT : vT);
    const size_t hb = (size_t)hh * NS;
    #pragma unroll
    for (int i = 0; i < 8; ++i) {
        B8 t;
        #pragma unroll
        for (int j = 0; j < 8; ++j) t.h[j] = f2b(acc[i][j]);
        *(floatx4*)&dstT[(hb + pos0 + tx*8 + i)*NHD + cc0] = t.v;
    }
}

// ---------------------------------------------------------------------------
// Kernel 2: 5x5x5 neighborhood attention with online softmax (one batch).
// Block = one (head, 2x4x4 query tile); 128 threads = 32 queries x 4
// channel-slices (8 ch each). k/v 6x8x8 halo (bf16) + pos_embed (f32) in
// LDS (63.6 KB). OOB neighbors: k=v=0 in LDS, pe still added -> matches
// reference zero-padding. aT aliases qT (same-thread read-before-write).
// ---------------------------------------------------------------------------
__global__ __launch_bounds__(128) void attn3d(
    const bfr* __restrict__ qT, const bfr* __restrict__ kT,
    const bfr* __restrict__ vT, const float* __restrict__ pe,
    bfr* __restrict__ aT)
{
    __shared__ __attribute__((aligned(16))) bfr   kl[384][32];   // 24 KB
    __shared__ __attribute__((aligned(16))) bfr   vl[384][32];   // 24 KB
    __shared__ __attribute__((aligned(16))) float pel[125][32];  // 15.6 KB
    const int tid = threadIdx.x;
    const int tz  = blockIdx.x >> 6;          // 16 z-tiles of 2
    const int tyy = (blockIdx.x >> 3) & 7;    // 8 y-tiles of 4
    const int txx = blockIdx.x & 7;           // 8 x-tiles of 4
    const size_t hb = (size_t)blockIdx.y * NS;

    // stage k halo (zero-fill OOB): 384 voxels, 3 per thread
    for (int hv = tid; hv < 384; hv += 128) {
        const int hz = hv >> 6, hy = (hv >> 3) & 7, hx = hv & 7;
        const int gz = tz*2 - 2 + hz, gy = tyy*4 - 2 + hy, gx = txx*4 - 2 + hx;
        floatx4* drow = (floatx4*)kl[hv];
        if ((unsigned)gz < 32u && (unsigned)gy < 32u && (unsigned)gx < 32u) {
            const floatx4* src =
                (const floatx4*)&kT[(hb + gz*1024 + gy*32 + gx)*NHD];
            #pragma unroll
            for (int r = 0; r < 4; ++r) drow[r] = src[r];
        } else {
            const floatx4 z = {0.f, 0.f, 0.f, 0.f};
            #pragma unroll
            for (int r = 0; r < 4; ++r) drow[r] = z;
        }
    }
    // stage v halo
    for (int hv = tid; hv < 384; hv += 128) {
        const int hz = hv >> 6, hy = (hv >> 3) & 7, hx = hv & 7;
        const int gz = tz*2 - 2 + hz, gy = tyy*4 - 2 + hy, gx = txx*4 - 2 + hx;
        floatx4* drow = (floatx4*)vl[hv];
        if ((unsigned)gz < 32u && (unsigned)gy < 32u && (unsigned)gx < 32u) {
            const floatx4* src =
                (const floatx4*)&vT[(hb + gz*1024 + gy*32 + gx)*NHD];
            #pragma unroll
            for (int r = 0; r < 4; ++r) drow[r] = src[r];
        } else {
            const floatx4 z = {0.f, 0.f, 0.f, 0.f};
            #pragma unroll
            for (int r = 0; r < 4; ++r) drow[r] = z;
        }
    }
    // stage pos_embed transposed: pel[n][c] = pe[c*125 + n]  (pe is f32)
    for (int e = tid; e < 4000; e += 128) {
        const int c = e / 125;
        const int n = e - c*125;
        pel[n][c] = pe[e];
    }

    const int qid = tid >> 2, t4 = tid & 3;       // 32 queries x 4 ch-slices
    const int qz = qid >> 4, qy = (qid >> 2) & 3, qx = qid & 3;
    const size_t sq = (size_t)(tz*2 + qz)*1024 + (tyy*4 + qy)*32 + (txx*4 + qx);
    float qf[8];
    {
        B8 t;
        t.v = *(const floatx4*)&qT[(hb + sq)*NHD + t4*8];
        #pragma unroll
        for (int j = 0; j < 8; ++j) qf[j] = b2f(t.h[j]);
    }
    __syncthreads();

    float m = -1e30f, l = 0.f;
    float acc[8];
    #pragma unroll
    for (int j = 0; j < 8; ++j) acc[j] = 0.f;

    int n = 0;
    for (int dz = 0; dz < 5; ++dz)
    for (int dy = 0; dy < 5; ++dy)
    for (int dx = 0; dx < 5; ++dx, ++n) {
        const int hv = (qz + dz)*64 + (qy + dy)*8 + (qx + dx);
        B8 kv, vv;
        F8 pv;
        kv.v = *(const floatx4*)&kl[hv][t4*8];
        pv.v[0] = *(const floatx4*)&pel[n][t4*8];
        pv.v[1] = *(const floatx4*)&pel[n][t4*8 + 4];
        float p = 0.f;
        #pragma unroll
        for (int j = 0; j < 8; ++j) p += qf[j] * (b2f(kv.h[j]) + pv.f[j]);
        p += __shfl_xor(p, 1);                 // reduce over the 4 ch-slices
        p += __shfl_xor(p, 2);
        const float s  = p * SCALE_F;
        const float mn = fmaxf(m, s);
        const float al = exp2f((m - mn) * LOG2E_F);
        const float ee = exp2f((s - mn) * LOG2E_F);
        l = l*al + ee;
        vv.v = *(const floatx4*)&vl[hv][t4*8];
        #pragma unroll
        for (int j = 0; j < 8; ++j) acc[j] = acc[j]*al + ee*b2f(vv.h[j]);
        m = mn;
    }
    const float rl = 1.f / l;
    B8 o;
    #pragma unroll
    for (int j = 0; j < 8; ++j) o.h[j] = f2b(acc[j] * rl);
    *(floatx4*)&aT[(hb + sq)*NHD + t4*8] = o.v;
}

// ---------------------------------------------------------------------------
// Kernel 3: proj GEMM (one batch). a[h][s][hd](bf16) * w[o][c](f32) + bias
// -> out[o][s] f32. K-chunk 32 == exactly one head.
// out points at d_out[b] (same region that held k — k already consumed).
// ---------------------------------------------------------------------------
__global__ __launch_bounds__(256) void proj_gemm(
    const bfr* __restrict__ aT, const float* __restrict__ w,
    const float* __restrict__ bias, float* __restrict__ out)
{
    __shared__ __attribute__((aligned(16))) float xs[32][256];   // 32 KB
    __shared__ __attribute__((aligned(16))) float wsh[32][64];   //  8 KB
    const int tid  = threadIdx.x;
    const int pos0 = blockIdx.x * 256;
    const int o0   = blockIdx.y * 64;
    const int tx = tid & 31, ty = tid >> 5;

    float acc[8][8];
    #pragma unroll
    for (int j = 0; j < 8; ++j) {
        const float bv = bias[o0 + ty*8 + j];
        #pragma unroll
        for (int i = 0; i < 8; ++i) acc[i][j] = bv;
    }

    for (int kc = 0; kc < 12; ++kc) {
        const size_t hbk = (size_t)kc * NS;
        // stage a chunk transposed into [ch][pos], bf16 -> f32
        #pragma unroll
        for (int r = 0; r < 4; ++r) {
            B8 t;
            t.v = *(const floatx4*)&aT[(hbk + pos0 + tid)*NHD + r*8];
            #pragma unroll
            for (int q = 0; q < 8; ++q) xs[r*8 + q][tid] = b2f(t.h[q]);
        }
        {
            const int j = tid >> 2, kg = tid & 3;
            F8 t;
            t.v[0] = *(const floatx4*)&w[(size_t)(o0 + j)*NC + kc*32 + kg*8];
            t.v[1] = *(const floatx4*)&w[(size_t)(o0 + j)*NC + kc*32 + kg*8 + 4];
            #pragma unroll
            for (int q = 0; q < 8; ++q) wsh[kg*8 + q][j] = t.f[q];
        }
        __syncthreads();
        #pragma unroll
        for (int kk = 0; kk < 32; ++kk) {
            F8 xv, wv;
            xv.v[0] = *(const floatx4*)&xs[kk][tx*8];
            xv.v[1] = *(const floatx4*)&xs[kk][tx*8 + 4];
            wv.v[0] = *(const floatx4*)&wsh[kk][ty*8];
            wv.v[1] = *(const floatx4*)&wsh[kk][ty*8 + 4];
            #pragma unroll
            for (int i = 0; i < 8; ++i)
                #pragma unroll
                for (int j = 0; j < 8; ++j)
                    acc[i][j] += xv.f[i] * wv.f[j];
        }
        __syncthreads();
    }

    // epilogue: channel-major f32 out, coalesced float4 stores
    #pragma unroll
    for (int j = 0; j < 8; ++j) {
        floatx4 s0 = {acc[0][j], acc[1][j], acc[2][j], acc[3][j]};
        floatx4 s1 = {acc[4][j], acc[5][j], acc[6][j], acc[7][j]};
        float* dst = &out[(size_t)(o0 + ty*8 + j)*NS + pos0 + tx*8];
        *(floatx4*)dst       = s0;
        *(floatx4*)(dst + 4) = s1;
    }
}

// ---------------------------------------------------------------------------
extern "C" void kernel_launch(void* const* d_in, const int* in_sizes, int n_in,
                              void* d_out, int out_size, void* d_ws, size_t ws_size,
                              hipStream_t stream)
{
    const float* x      = (const float*)d_in[0];
    const float* w_qkv  = (const float*)d_in[1];
    const float* b_qkv  = (const float*)d_in[2];
    const float* w_proj = (const float*)d_in[3];
    const float* b_proj = (const float*)d_in[4];
    const float* pe     = (const float*)d_in[5];
    float* outp = (float*)d_out;

    const size_t NEED = (size_t)2 * PERB * sizeof(bfr);  // 48 MiB
    if (ws_size < NEED) {
        // ws too small: encode ws_size (in MiB) into the output as a probe
        fill_code<<<2048, 256, 0, stream>>>(outp, (float)(ws_size >> 20));
        return;
    }

    bfr* qT = (bfr*)d_ws;          // ws[0 .. PERB)      (aT aliases this)
    bfr* vT = qT + PERB;           // ws[PERB .. 2*PERB)

    for (int b = 0; b < NB; ++b) {
        // k scratch lives in d_out's batch-b half (PERB floats >= PERB bf16)
        bfr* kT = (bfr*)(outp + (size_t)b * PERB);
        bfr* aT = qT;
        qkv_gemm<<<dim3(128, 18, 1), 256, 0, stream>>>(
            x, w_qkv, b_qkv, qT, kT, vT, b);
        attn3d<<<dim3(1024, 12, 1), 128, 0, stream>>>(qT, kT, vT, pe, aT);
        proj_gemm<<<dim3(128, 6, 1), 256, 0, stream>>>(
            aT, w_proj, b_proj, outp + (size_t)b * PERB);
    }
}

// Round 5
// 1583.251 us; speedup vs baseline: 1.3706x; 1.3706x over previous
//
#include <hip/hip_runtime.h>

// ---------------------------------------------------------------------------
// SpatialAttention3D: B=2, C=384, D=H=W=32, HEADS=12, HD=32, WS=5, PAD=2
// I/O dtype: float32. Intermediates q/k/v/a: bf16.
// R5: qkv & proj GEMMs moved to MFMA (v_mfma_f32_16x16x32_bf16).
//   per batch b:
//     1: qkv_mfma: x[b](f32) @ w_qkv^T + b -> q (ws), k (d_out[b]), v (ws)
//     2: attn3d (unchanged from R4)        -> a (aliases q)
//     3: proj_mfma: a(bf16) @ w_proj^T + b -> d_out[b] f32
// MFMA tile: block = 128o x 128s, 4 waves in 2x2, wave = 64x64 = 4x4 MFMA.
// A-frag (w): [o][c] c-contig; B-frag (x/a): [s][c] c-contig; both staged in
// LDS with rows padded to 40 elems (80B) -> 16B-aligned b128, 2-way-max banks.
// ---------------------------------------------------------------------------

#define NB 2
#define NC 384
#define NHEADS 12
#define NHD 32
#define NS 32768               // 32*32*32
#define PERB 12582912          // NC*NS (one batch of out / qkv third)
#define SCALE_F 0.17677669529663687f
#define LOG2E_F 1.4426950408889634f

typedef unsigned short bfr;    // raw bf16 bits
typedef float floatx4 __attribute__((ext_vector_type(4)));
typedef float f32x4 __attribute__((ext_vector_type(4)));
typedef short bf16x8 __attribute__((ext_vector_type(8)));   // 8 bf16 = 1 b128
typedef short short4v __attribute__((ext_vector_type(4)));  // 4 bf16 = 1 b64

union F8 { floatx4 v[2]; float f[8]; };
union B8 { floatx4 v;    bfr  h[8]; };

__device__ __forceinline__ float b2f(bfr u) {
    union { unsigned int i; float f; } v;
    v.i = (unsigned int)u << 16;
    return v.f;
}
__device__ __forceinline__ bfr f2b(float f) {
    union { float f; unsigned int i; } v;
    v.f = f;
    unsigned int x = v.i;
    return (bfr)((x + 0x7fffu + ((x >> 16) & 1u)) >> 16);  // RNE
}

// diagnostic: encode ws_size (MiB) into the output if ws is too small
__global__ void fill_code(float* out, float code) {
    for (size_t i = (size_t)blockIdx.x*256 + threadIdx.x; i < (size_t)NB*PERB;
         i += (size_t)gridDim.x*256) out[i] = code;
}

// ---------------------------------------------------------------------------
// Kernel 1: QKV GEMM, MFMA. grid (256 s-tiles, 9 o-tiles), 256 threads.
// o-blocks 0..2 -> q, 3..5 -> k, 6..8 -> v (128 o = 4 heads each, exact).
// ---------------------------------------------------------------------------
__global__ __launch_bounds__(256) void qkv_mfma(
    const float* __restrict__ x, const float* __restrict__ w,
    const float* __restrict__ bias,
    bfr* __restrict__ qT, bfr* __restrict__ kT, bfr* __restrict__ vT, int b)
{
    __shared__ __attribute__((aligned(16))) bfr wl[128*40];   // [o][c] pad40
    __shared__ __attribute__((aligned(16))) bfr xl[128*40];   // [s][c] pad40
    __shared__ float bsh[128];
    const int tid  = threadIdx.x;
    const int lane = tid & 63;
    const int wave = tid >> 6;
    const int wo   = (wave & 1) * 64;     // wave o-quadrant
    const int wsq  = (wave >> 1) * 64;    // wave s-quadrant
    const int s0   = blockIdx.x * 128;
    const int o0   = blockIdx.y * 128;
    const int m16  = lane & 15;           // fragment row/col index
    const int g    = lane >> 4;           // k-chunk quarter (0..3)

    if (tid < 128) bsh[tid] = bias[o0 + tid];

    f32x4 acc[4][4];
    #pragma unroll
    for (int i = 0; i < 4; ++i)
        #pragma unroll
        for (int j = 0; j < 4; ++j) acc[i][j] = (f32x4){0.f, 0.f, 0.f, 0.f};

    for (int kc = 0; kc < 12; ++kc) {
        const int c0 = kc * 32;
        // stage w tile [128 o][32 c] f32->bf16 (1024 float4, 4 per thread)
        #pragma unroll
        for (int r = 0; r < 4; ++r) {
            const int idx = r*256 + tid;
            const int o   = idx >> 3;
            const int c4  = (idx & 7) * 4;
            floatx4 wv = *(const floatx4*)&w[(size_t)(o0 + o)*NC + c0 + c4];
            short4v t;
            t[0] = (short)f2b(wv[0]); t[1] = (short)f2b(wv[1]);
            t[2] = (short)f2b(wv[2]); t[3] = (short)f2b(wv[3]);
            *(short4v*)&wl[o*40 + c4] = t;
        }
        // stage x tile transposed: [32 c][128 s] f32 -> LDS [s][c] bf16
        #pragma unroll
        for (int r = 0; r < 4; ++r) {
            const int idx = r*256 + tid;
            const int c   = idx >> 5;
            const int s4  = (idx & 31) * 4;
            floatx4 xv =
                *(const floatx4*)&x[((size_t)b*NC + c0 + c)*NS + s0 + s4];
            #pragma unroll
            for (int i = 0; i < 4; ++i) xl[(s4 + i)*40 + c] = f2b(xv[i]);
        }
        __syncthreads();
        bf16x8 af[4], bfg[4];
        #pragma unroll
        for (int i = 0; i < 4; ++i)
            af[i] = *(bf16x8*)&wl[(wo + i*16 + m16)*40 + g*8];
        #pragma unroll
        for (int j = 0; j < 4; ++j)
            bfg[j] = *(bf16x8*)&xl[(wsq + j*16 + m16)*40 + g*8];
        #pragma unroll
        for (int i = 0; i < 4; ++i)
            #pragma unroll
            for (int j = 0; j < 4; ++j)
                acc[i][j] = __builtin_amdgcn_mfma_f32_16x16x32_bf16(
                    af[i], bfg[j], acc[i][j], 0, 0, 0);
        __syncthreads();
    }

    // epilogue: +bias, bf16, heads layout. tensor uniform per block.
    const int tens = blockIdx.y / 3;            // 0=q,1=k,2=v
    bfr* dstT = (tens == 0) ? qT : ((tens == 1) ? kT : vT);
    const int remb = o0 - tens*NC;              // o offset within tensor
    const int q4   = g * 4;                     // C-layout row group
    #pragma unroll
    for (int i = 0; i < 4; ++i) {
        const int olb = wo + i*16 + q4;         // block-local o (mult of 4)
        const int ob  = remb + olb;
        const int hh  = ob >> 5;
        const int cc  = ob & 31;
        #pragma unroll
        for (int j = 0; j < 4; ++j) {
            const int s = s0 + wsq + j*16 + m16;
            short4v t;
            #pragma unroll
            for (int r = 0; r < 4; ++r)
                t[r] = (short)f2b(acc[i][j][r] + bsh[olb + r]);
            *(short4v*)&dstT[((size_t)hh*NS + s)*NHD + cc] = t;
        }
    }
}

// ---------------------------------------------------------------------------
// Kernel 2: attn3d — UNCHANGED from R4 (byte-identical logic).
// ---------------------------------------------------------------------------
__global__ __launch_bounds__(128) void attn3d(
    const bfr* __restrict__ qT, const bfr* __restrict__ kT,
    const bfr* __restrict__ vT, const float* __restrict__ pe,
    bfr* __restrict__ aT)
{
    __shared__ __attribute__((aligned(16))) bfr   kl[384][32];   // 24 KB
    __shared__ __attribute__((aligned(16))) bfr   vl[384][32];   // 24 KB
    __shared__ __attribute__((aligned(16))) float pel[125][32];  // 15.6 KB
    const int tid = threadIdx.x;
    const int tz  = blockIdx.x >> 6;
    const int tyy = (blockIdx.x >> 3) & 7;
    const int txx = blockIdx.x & 7;
    const size_t hb = (size_t)blockIdx.y * NS;

    for (int hv = tid; hv < 384; hv += 128) {
        const int hz = hv >> 6, hy = (hv >> 3) & 7, hx = hv & 7;
        const int gz = tz*2 - 2 + hz, gy = tyy*4 - 2 + hy, gx = txx*4 - 2 + hx;
        floatx4* drow = (floatx4*)kl[hv];
        if ((unsigned)gz < 32u && (unsigned)gy < 32u && (unsigned)gx < 32u) {
            const floatx4* src =
                (const floatx4*)&kT[(hb + gz*1024 + gy*32 + gx)*NHD];
            #pragma unroll
            for (int r = 0; r < 4; ++r) drow[r] = src[r];
        } else {
            const floatx4 z = {0.f, 0.f, 0.f, 0.f};
            #pragma unroll
            for (int r = 0; r < 4; ++r) drow[r] = z;
        }
    }
    for (int hv = tid; hv < 384; hv += 128) {
        const int hz = hv >> 6, hy = (hv >> 3) & 7, hx = hv & 7;
        const int gz = tz*2 - 2 + hz, gy = tyy*4 - 2 + hy, gx = txx*4 - 2 + hx;
        floatx4* drow = (floatx4*)vl[hv];
        if ((unsigned)gz < 32u && (unsigned)gy < 32u && (unsigned)gx < 32u) {
            const floatx4* src =
                (const floatx4*)&vT[(hb + gz*1024 + gy*32 + gx)*NHD];
            #pragma unroll
            for (int r = 0; r < 4; ++r) drow[r] = src[r];
        } else {
            const floatx4 z = {0.f, 0.f, 0.f, 0.f};
            #pragma unroll
            for (int r = 0; r < 4; ++r) drow[r] = z;
        }
    }
    for (int e = tid; e < 4000; e += 128) {
        const int c = e / 125;
        const int n = e - c*125;
        pel[n][c] = pe[e];
    }

    const int qid = tid >> 2, t4 = tid & 3;
    const int qz = qid >> 4, qy = (qid >> 2) & 3, qx = qid & 3;
    const size_t sq = (size_t)(tz*2 + qz)*1024 + (tyy*4 + qy)*32 + (txx*4 + qx);
    float qf[8];
    {
        B8 t;
        t.v = *(const floatx4*)&qT[(hb + sq)*NHD + t4*8];
        #pragma unroll
        for (int j = 0; j < 8; ++j) qf[j] = b2f(t.h[j]);
    }
    __syncthreads();

    float m = -1e30f, l = 0.f;
    float acc[8];
    #pragma unroll
    for (int j = 0; j < 8; ++j) acc[j] = 0.f;

    int n = 0;
    for (int dz = 0; dz < 5; ++dz)
    for (int dy = 0; dy < 5; ++dy)
    for (int dx = 0; dx < 5; ++dx, ++n) {
        const int hv = (qz + dz)*64 + (qy + dy)*8 + (qx + dx);
        B8 kv, vv;
        F8 pv;
        kv.v = *(const floatx4*)&kl[hv][t4*8];
        pv.v[0] = *(const floatx4*)&pel[n][t4*8];
        pv.v[1] = *(const floatx4*)&pel[n][t4*8 + 4];
        float p = 0.f;
        #pragma unroll
        for (int j = 0; j < 8; ++j) p += qf[j] * (b2f(kv.h[j]) + pv.f[j]);
        p += __shfl_xor(p, 1);
        p += __shfl_xor(p, 2);
        const float s  = p * SCALE_F;
        const float mn = fmaxf(m, s);
        const float al = exp2f((m - mn) * LOG2E_F);
        const float ee = exp2f((s - mn) * LOG2E_F);
        l = l*al + ee;
        vv.v = *(const floatx4*)&vl[hv][t4*8];
        #pragma unroll
        for (int j = 0; j < 8; ++j) acc[j] = acc[j]*al + ee*b2f(vv.h[j]);
        m = mn;
    }
    const float rl = 1.f / l;
    B8 o;
    #pragma unroll
    for (int j = 0; j < 8; ++j) o.h[j] = f2b(acc[j] * rl);
    *(floatx4*)&aT[(hb + sq)*NHD + t4*8] = o.v;
}

// ---------------------------------------------------------------------------
// Kernel 3: proj GEMM, MFMA. grid (256 s-tiles, 3 o-tiles), 256 threads.
// B operand (aT) is already [s][c]-contiguous per head -> pure b128 staging.
// ---------------------------------------------------------------------------
__global__ __launch_bounds__(256) void proj_mfma(
    const bfr* __restrict__ aT, const float* __restrict__ w,
    const float* __restrict__ bias, float* __restrict__ out)
{
    __shared__ __attribute__((aligned(16))) bfr wl[128*40];   // [o][c] pad40
    __shared__ __attribute__((aligned(16))) bfr xl[128*40];   // [s][c] pad40
    __shared__ float bsh[128];
    const int tid  = threadIdx.x;
    const int lane = tid & 63;
    const int wave = tid >> 6;
    const int wo   = (wave & 1) * 64;
    const int wsq  = (wave >> 1) * 64;
    const int s0   = blockIdx.x * 128;
    const int o0   = blockIdx.y * 128;
    const int m16  = lane & 15;
    const int g    = lane >> 4;

    if (tid < 128) bsh[tid] = bias[o0 + tid];

    f32x4 acc[4][4];
    #pragma unroll
    for (int i = 0; i < 4; ++i)
        #pragma unroll
        for (int j = 0; j < 4; ++j) acc[i][j] = (f32x4){0.f, 0.f, 0.f, 0.f};

    for (int kc = 0; kc < 12; ++kc) {          // kc == head
        const int c0 = kc * 32;
        // stage w tile [128 o][32 c] f32->bf16
        #pragma unroll
        for (int r = 0; r < 4; ++r) {
            const int idx = r*256 + tid;
            const int o   = idx >> 3;
            const int c4  = (idx & 7) * 4;
            floatx4 wv = *(const floatx4*)&w[(size_t)(o0 + o)*NC + c0 + c4];
            short4v t;
            t[0] = (short)f2b(wv[0]); t[1] = (short)f2b(wv[1]);
            t[2] = (short)f2b(wv[2]); t[3] = (short)f2b(wv[3]);
            *(short4v*)&wl[o*40 + c4] = t;
        }
        // stage a tile: [128 s][32 c] bf16, direct b128 copies (512, 2/thread)
        #pragma unroll
        for (int r = 0; r < 2; ++r) {
            const int idx = r*256 + tid;
            const int s   = idx >> 2;
            const int gg  = idx & 3;
            *(floatx4*)&xl[s*40 + gg*8] =
                *(const floatx4*)&aT[((size_t)kc*NS + s0 + s)*NHD + gg*8];
        }
        __syncthreads();
        bf16x8 af[4], bfg[4];
        #pragma unroll
        for (int i = 0; i < 4; ++i)
            af[i] = *(bf16x8*)&wl[(wo + i*16 + m16)*40 + g*8];
        #pragma unroll
        for (int j = 0; j < 4; ++j)
            bfg[j] = *(bf16x8*)&xl[(wsq + j*16 + m16)*40 + g*8];
        #pragma unroll
        for (int i = 0; i < 4; ++i)
            #pragma unroll
            for (int j = 0; j < 4; ++j)
                acc[i][j] = __builtin_amdgcn_mfma_f32_16x16x32_bf16(
                    af[i], bfg[j], acc[i][j], 0, 0, 0);
        __syncthreads();
    }

    // epilogue: +bias, f32 channel-major out[o][s]
    const int q4 = g * 4;
    #pragma unroll
    for (int i = 0; i < 4; ++i) {
        const int olb = wo + i*16 + q4;
        #pragma unroll
        for (int j = 0; j < 4; ++j) {
            const int s = s0 + wsq + j*16 + m16;
            #pragma unroll
            for (int r = 0; r < 4; ++r)
                out[(size_t)(o0 + olb + r)*NS + s] = acc[i][j][r] + bsh[olb + r];
        }
    }
}

// ---------------------------------------------------------------------------
extern "C" void kernel_launch(void* const* d_in, const int* in_sizes, int n_in,
                              void* d_out, int out_size, void* d_ws, size_t ws_size,
                              hipStream_t stream)
{
    const float* x      = (const float*)d_in[0];
    const float* w_qkv  = (const float*)d_in[1];
    const float* b_qkv  = (const float*)d_in[2];
    const float* w_proj = (const float*)d_in[3];
    const float* b_proj = (const float*)d_in[4];
    const float* pe     = (const float*)d_in[5];
    float* outp = (float*)d_out;

    const size_t NEED = (size_t)2 * PERB * sizeof(bfr);  // 48 MiB
    if (ws_size < NEED) {
        fill_code<<<2048, 256, 0, stream>>>(outp, (float)(ws_size >> 20));
        return;
    }

    bfr* qT = (bfr*)d_ws;          // ws[0 .. PERB)      (aT aliases this)
    bfr* vT = qT + PERB;           // ws[PERB .. 2*PERB)

    for (int b = 0; b < NB; ++b) {
        bfr* kT = (bfr*)(outp + (size_t)b * PERB);  // d_out batch half
        bfr* aT = qT;
        qkv_mfma<<<dim3(256, 9, 1), 256, 0, stream>>>(
            x, w_qkv, b_qkv, qT, kT, vT, b);
        attn3d<<<dim3(1024, 12, 1), 128, 0, stream>>>(qT, kT, vT, pe, aT);
        proj_mfma<<<dim3(256, 3, 1), 256, 0, stream>>>(
            aT, w_proj, b_proj, outp + (size_t)b * PERB);
    }
}